// Round 1
// baseline (8984.711 us; speedup 1.0000x reference)
//
#include <hip/hip_runtime.h>
#include <stdint.h>

// Farthest Point Sampling, B=8, N=131072, npoint=1024.
// 8 batches x 32 WGs x 256 threads; 16 points/thread held in registers.
// Cross-WG per-iteration sync via tagged slots in d_ws (agent-scope atomics, L3-coherent).

#define NPTS        131072
#define NBATCH      8
#define WGB         32          // workgroups per batch
#define THREADS     256
#define PPT         16          // points per thread = NPTS / (WGB*THREADS)
#define BIGDIST     1e10f

__global__ __launch_bounds__(THREADS) void fps_kernel(
        const float* __restrict__ xyz,          // [B, N, 3]
        int* __restrict__ out,                  // [B, npoint]
        unsigned long long* __restrict__ slots, // [2][NBATCH][WGB]
        int npoint)
{
    const int bid  = blockIdx.x;
    const int b    = bid & 7;       // batch (spreads a batch's WGs across XCDs)
    const int w    = bid >> 3;      // 0..31 WG-within-batch
    const int tid  = threadIdx.x;
    const int lane = tid & 63;
    const int wave = tid >> 6;      // 0..3

    const int p0 = w * (THREADS * PPT) + tid * PPT;    // first owned point (within batch)
    const float* base = xyz + (size_t)b * NPTS * 3;

    // ---- load my 16 points into registers (48 floats = 12 float4, one-time) ----
    float px[PPT], py[PPT], pz[PPT], dist[PPT];
    {
        const float4* src = reinterpret_cast<const float4*>(base + (size_t)p0 * 3);
        float f[PPT * 3];
        #pragma unroll
        for (int q = 0; q < (PPT * 3) / 4; ++q) {
            float4 v = src[q];
            f[q*4+0] = v.x; f[q*4+1] = v.y; f[q*4+2] = v.z; f[q*4+3] = v.w;
        }
        #pragma unroll
        for (int j = 0; j < PPT; ++j) {
            px[j] = f[3*j]; py[j] = f[3*j+1]; pz[j] = f[3*j+2];
            dist[j] = BIGDIST;
        }
    }

    __shared__ float s_wv[THREADS/64];
    __shared__ int   s_wi[THREADS/64];
    __shared__ float s_c[3];
    __shared__ int   s_f;

    // initial centroid = point 0 of this batch (farthest starts at 0)
    float cx = base[0], cy = base[1], cz = base[2];
    int farthest = 0;

    unsigned long long* slots0 = slots + ((size_t)0 * NBATCH + b) * WGB;
    unsigned long long* slots1 = slots + ((size_t)1 * NBATCH + b) * WGB;

    for (int i = 0; i < npoint; ++i) {
        // emit the index selected BEFORE this iteration's update (scan semantics)
        if (w == 0 && tid == 0) out[b * npoint + i] = farthest;

        // ---- distance min-update + per-thread argmax (pure register compute) ----
        float bv = -1.0f; int bj = 0;
        {
            #pragma clang fp contract(off)
            #pragma unroll
            for (int j = 0; j < PPT; ++j) {
                float dx = px[j] - cx, dy = py[j] - cy, dz = pz[j] - cz;
                float d  = dx*dx + dy*dy + dz*dz;     // mul/add, no fma (match XLA)
                float nd = fminf(dist[j], d);
                dist[j]  = nd;
                if (nd > bv) { bv = nd; bj = j; }     // strict > keeps first index
            }
        }
        int bidx = p0 + bj;

        // ---- wave butterfly argmax (tie -> smaller index) ----
        #pragma unroll
        for (int m = 32; m >= 1; m >>= 1) {
            float ov = __shfl_xor(bv, m);
            int   oi = __shfl_xor(bidx, m);
            if (ov > bv || (ov == bv && oi < bidx)) { bv = ov; bidx = oi; }
        }
        if (lane == 0) { s_wv[wave] = bv; s_wi[wave] = bidx; }
        __syncthreads();

        // ---- thread 0: cross-wave reduce, publish packed slot ----
        unsigned long long* sb = (i & 1) ? slots1 : slots0;
        if (tid == 0) {
            float v = s_wv[0]; int ix = s_wi[0];
            #pragma unroll
            for (int q = 1; q < THREADS/64; ++q) {
                float ov = s_wv[q]; int oi = s_wi[q];
                if (ov > v || (ov == v && oi < ix)) { v = ov; ix = oi; }
            }
            // pack: [63:32] float bits (positive -> order-preserving)
            //       [26:17] iteration tag (i+1, 10 bits)
            //       [16:0]  131071 - idx  (bigger packed == smaller idx on value tie)
            unsigned long long pk =
                  ((unsigned long long)__float_as_uint(v) << 32)
                | ((unsigned long long)((unsigned)(i + 1) & 1023u) << 17)
                | (unsigned long long)(0x1FFFFu - (unsigned)ix);
            __hip_atomic_store(sb + w, pk, __ATOMIC_RELEASE, __HIP_MEMORY_SCOPE_AGENT);
        }

        // ---- wave 0: poll all 32 slots, reduce, fetch winner coords ----
        if (wave == 0) {
            unsigned long long* sl = sb + (lane & 31);
            const unsigned wanttag = (unsigned)(i + 1) & 1023u;
            unsigned long long s;
            do {
                s = __hip_atomic_load(sl, __ATOMIC_ACQUIRE, __HIP_MEMORY_SCOPE_AGENT);
            } while ((unsigned)((s >> 17) & 1023u) != wanttag);

            int idx_l = (int)(0x1FFFFu - (unsigned)(s & 0x1FFFFu));
            // speculative coord fetch for my candidate (overlaps the reduce)
            const float* cp = base + (size_t)idx_l * 3;
            float ccx = cp[0], ccy = cp[1], ccz = cp[2];

            unsigned long long mx = s;
            #pragma unroll
            for (int m = 32; m >= 1; m >>= 1) {
                unsigned long long o = __shfl_xor(mx, m);
                if (o > mx) mx = o;
            }
            unsigned long long ball = __ballot(s == mx);
            int winlane = __ffsll(ball) - 1;
            float wx = __shfl(ccx, winlane);
            float wy = __shfl(ccy, winlane);
            float wz = __shfl(ccz, winlane);
            int  wix = __shfl(idx_l, winlane);
            if (lane == 0) { s_c[0] = wx; s_c[1] = wy; s_c[2] = wz; s_f = wix; }
        }
        __syncthreads();

        cx = s_c[0]; cy = s_c[1]; cz = s_c[2];
        farthest = s_f;
    }
}

extern "C" void kernel_launch(void* const* d_in, const int* in_sizes, int n_in,
                              void* d_out, int out_size, void* d_ws, size_t ws_size,
                              hipStream_t stream) {
    const float* xyz = (const float*)d_in[0];
    int* out = (int*)d_out;
    unsigned long long* slots = (unsigned long long*)d_ws;
    const int npoint = out_size / NBATCH;   // 1024

    // Clear slot region (4 KB) so stale/poisoned tags can never match.
    hipMemsetAsync(d_ws, 0, (size_t)2 * NBATCH * WGB * sizeof(unsigned long long), stream);

    dim3 grid(NBATCH * WGB);   // 256 WGs <= 256 CUs -> all co-resident, spin-sync safe
    dim3 block(THREADS);
    fps_kernel<<<grid, block, 0, stream>>>(xyz, out, slots, npoint);
}

// Round 2
// 2669.294 us; speedup vs baseline: 3.3659x; 3.3659x over previous
//
#include <hip/hip_runtime.h>
#include <stdint.h>

// Farthest Point Sampling, B=8, N=131072, npoint=1024.
// 8 batches x 8 WGs x 512 threads; 32 points/thread held in registers.
// Cross-WG per-iteration sync via tagged, cache-line-padded slots in d_ws
// (relaxed agent-scope atomics -- the 64-bit slot word is the entire payload).

#define NPTS        131072
#define NBATCH      8
#define WGB         8           // workgroups per batch
#define THREADS     512
#define PPT         32          // points per thread = NPTS / (WGB*THREADS)
#define SLOT_STRIDE 16          // ULLs per slot = 128 B (own cache line)
#define BIGDIST     1e10f

__global__ __launch_bounds__(THREADS, 2) void fps_kernel(
        const float* __restrict__ xyz,          // [B, N, 3]
        int* __restrict__ out,                  // [B, npoint]
        unsigned long long* __restrict__ slots, // [2][NBATCH][WGB][SLOT_STRIDE]
        int npoint)
{
    const int bid  = blockIdx.x;
    const int b    = bid & (NBATCH - 1);  // consecutive bids -> same batch on one XCD
    const int w    = bid >> 3;            // 0..7 WG-within-batch
    const int tid  = threadIdx.x;
    const int lane = tid & 63;
    const int wave = tid >> 6;            // 0..7

    const int p0 = w * (THREADS * PPT) + tid * PPT;   // first owned point (within batch)
    const float* base = xyz + (size_t)b * NPTS * 3;

    // ---- one-time load: 32 points (96 floats = 24 float4) into registers ----
    float px[PPT], py[PPT], pz[PPT], dist[PPT];
    {
        const float4* src = reinterpret_cast<const float4*>(base + (size_t)p0 * 3);
        float f[PPT * 3];
        #pragma unroll
        for (int q = 0; q < (PPT * 3) / 4; ++q) {
            float4 v = src[q];
            f[4*q+0] = v.x; f[4*q+1] = v.y; f[4*q+2] = v.z; f[4*q+3] = v.w;
        }
        #pragma unroll
        for (int j = 0; j < PPT; ++j) {
            px[j] = f[3*j]; py[j] = f[3*j+1]; pz[j] = f[3*j+2];
            dist[j] = BIGDIST;
        }
    }

    __shared__ unsigned long long s_w[THREADS / 64];  // per-wave reduced packed
    __shared__ float s_c[3];                          // winner coords broadcast

    // initial centroid = point 0 of this batch
    float cx = base[0], cy = base[1], cz = base[2];

    if (w == 0 && tid == 0) out[b * npoint + 0] = 0;

    const size_t PAR = (size_t)NBATCH * WGB * SLOT_STRIDE;  // parity block (ULLs)

    for (int i = 0; i < npoint - 1; ++i) {
        // ---- distance min-update + per-thread argmax (pure register compute) ----
        float bv = -1.0f; int bj = 0;
        {
            #pragma clang fp contract(off)
            #pragma unroll
            for (int j = 0; j < PPT; ++j) {
                float dx = px[j] - cx, dy = py[j] - cy, dz = pz[j] - cz;
                float d  = dx*dx + dy*dy + dz*dz;     // mul/add order matches ref
                float nd = fminf(dist[j], d);
                dist[j]  = nd;
                if (nd > bv) { bv = nd; bj = j; }     // strict > keeps first index
            }
        }
        // pack: [63:32] float bits (non-neg -> order-preserving)
        //       [16:0]  131071 - idx  (bigger packed == smaller idx on tie)
        //       bits [31:22] reserved for tag at publish time (zero here)
        unsigned long long pk =
              ((unsigned long long)__float_as_uint(bv) << 32)
            | (unsigned long long)(0x1FFFFu - (unsigned)(p0 + bj));

        // ---- wave butterfly max on packed u64 ----
        #pragma unroll
        for (int m = 32; m >= 1; m >>= 1) {
            unsigned long long o = __shfl_xor(pk, m);
            if (o > pk) pk = o;
        }
        if (lane == 0) s_w[wave] = pk;
        __syncthreads();

        unsigned long long* sb =
            slots + ((i & 1) ? PAR : (size_t)0) + (size_t)b * WGB * SLOT_STRIDE;
        const unsigned tag = (unsigned)(i + 1);   // 1..1023, fits 10 bits, never 0

        if (wave == 0) {
            // ---- cross-wave reduce: lanes 0..7 each grab one wave's result ----
            unsigned long long v = s_w[lane & 7];
            #pragma unroll
            for (int m = 4; m >= 1; m >>= 1) {
                unsigned long long o = __shfl_xor(v, m);
                if (o > v) v = o;
            }
            // ---- lane 0 publishes (tag in bits [31:22]); relaxed is sufficient:
            //      the slot word is the entire communicated payload ----
            if (lane == 0) {
                unsigned long long pub = v | ((unsigned long long)tag << 22);
                __hip_atomic_store(sb + (size_t)w * SLOT_STRIDE, pub,
                                   __ATOMIC_RELAXED, __HIP_MEMORY_SCOPE_AGENT);
            }
            // ---- lanes 0..7 poll the 8 padded slots ----
            unsigned long long s = 0;
            if (lane < WGB) {
                unsigned long long* sl = sb + (size_t)lane * SLOT_STRIDE;
                do {
                    s = __hip_atomic_load(sl, __ATOMIC_RELAXED,
                                          __HIP_MEMORY_SCOPE_AGENT);
                } while (((unsigned)(s >> 22) & 1023u) != tag);
            }
            // speculative candidate-coords fetch (overlaps the reduce)
            int idx_l = (int)(0x1FFFFu - (unsigned)(s & 0x1FFFFu));
            float ccx = 0.f, ccy = 0.f, ccz = 0.f;
            if (lane < WGB) {
                const float* cp = base + (size_t)idx_l * 3;
                ccx = cp[0]; ccy = cp[1]; ccz = cp[2];
            }
            // ---- reduce over the 8 slot values (tags equal -> order by val,idx) ----
            unsigned long long mx = s;
            #pragma unroll
            for (int m = 4; m >= 1; m >>= 1) {
                unsigned long long o = __shfl_xor(mx, m);
                if (o > mx) mx = o;
            }
            unsigned long long ball = __ballot(lane < WGB && s == mx);
            int winlane = __ffsll(ball) - 1;
            float wx = __shfl(ccx, winlane);
            float wy = __shfl(ccy, winlane);
            float wz = __shfl(ccz, winlane);
            int  wix = __shfl(idx_l, winlane);
            if (lane == 0) {
                s_c[0] = wx; s_c[1] = wy; s_c[2] = wz;
                if (w == 0) out[b * npoint + (i + 1)] = wix;
            }
        }
        __syncthreads();

        cx = s_c[0]; cy = s_c[1]; cz = s_c[2];
    }
}

extern "C" void kernel_launch(void* const* d_in, const int* in_sizes, int n_in,
                              void* d_out, int out_size, void* d_ws, size_t ws_size,
                              hipStream_t stream) {
    const float* xyz = (const float*)d_in[0];
    int* out = (int*)d_out;
    unsigned long long* slots = (unsigned long long*)d_ws;
    const int npoint = out_size / NBATCH;   // 1024

    // Clear slot region (16 KB) so stale/poisoned tags can never match tag>=1.
    hipMemsetAsync(d_ws, 0,
                   (size_t)2 * NBATCH * WGB * SLOT_STRIDE * sizeof(unsigned long long),
                   stream);

    dim3 grid(NBATCH * WGB);   // 64 WGs, all co-resident -> spin-sync safe
    dim3 block(THREADS);
    fps_kernel<<<grid, block, 0, stream>>>(xyz, out, slots, npoint);
}

// Round 3
// 2667.336 us; speedup vs baseline: 3.3684x; 1.0007x over previous
//
#include <hip/hip_runtime.h>
#include <stdint.h>

// Farthest Point Sampling, B=8, N=131072, npoint=1024.
// 8 batches x 8 WGs x 512 threads; 32 points/thread held in registers
// (asm-pinned so hipcc cannot rematerialize the loads per iteration).
// Cross-WG per-iteration sync via tagged, cache-line-padded slots in d_ws
// (relaxed agent-scope atomics -- the 64-bit slot word is the entire payload).

#define NPTS        131072
#define NBATCH      8
#define WGB         8           // workgroups per batch
#define THREADS     512
#define PPT         32          // points per thread = NPTS / (WGB*THREADS)
#define SLOT_STRIDE 16          // ULLs per slot = 128 B (own cache line)
#define BIGDIST     1e10f

__global__ __launch_bounds__(THREADS, 2) void fps_kernel(
        const float* __restrict__ xyz,          // [B, N, 3]
        int* __restrict__ out,                  // [B, npoint]
        unsigned long long* __restrict__ slots, // [2][NBATCH][WGB][SLOT_STRIDE]
        int npoint)
{
    const int bid  = blockIdx.x;
    const int b    = bid & (NBATCH - 1);  // bid%8 -> batch: one XCD per batch (perf heuristic)
    const int w    = bid >> 3;            // 0..7 WG-within-batch
    const int tid  = threadIdx.x;
    const int lane = tid & 63;
    const int wave = tid >> 6;            // 0..7

    const int p0 = w * (THREADS * PPT) + tid * PPT;   // first owned point (within batch)
    const float* base = xyz + (size_t)b * NPTS * 3;

    // ---- one-time load: 32 points (96 floats = 24 float4) into registers ----
    float px[PPT], py[PPT], pz[PPT], dist[PPT];
    {
        const float4* src = reinterpret_cast<const float4*>(base + (size_t)p0 * 3);
        float f[PPT * 3];
        #pragma unroll
        for (int q = 0; q < (PPT * 3) / 4; ++q) {
            float4 v = src[q];
            f[4*q+0] = v.x; f[4*q+1] = v.y; f[4*q+2] = v.z; f[4*q+3] = v.w;
        }
        #pragma unroll
        for (int j = 0; j < PPT; ++j) {
            px[j] = f[3*j]; py[j] = f[3*j+1]; pz[j] = f[3*j+2];
            dist[j] = BIGDIST;
        }
    }
    // Pin coordinates in VGPRs: the asm is an opaque def, so the compiler can
    // no longer rematerialize the global loads inside the iteration loop
    // (VGPR_Count=76 in round 2 proved it was re-reading ~12.6 MB/iter from L2).
    #pragma unroll
    for (int j = 0; j < PPT; ++j) {
        asm volatile("" : "+v"(px[j]), "+v"(py[j]), "+v"(pz[j]));
    }

    __shared__ unsigned long long s_w[THREADS / 64];  // per-wave reduced packed
    __shared__ float s_c[3];                          // winner coords broadcast

    // initial centroid = point 0 of this batch
    float cx = base[0], cy = base[1], cz = base[2];

    if (w == 0 && tid == 0) out[b * npoint + 0] = 0;

    const size_t PAR = (size_t)NBATCH * WGB * SLOT_STRIDE;  // parity block (ULLs)

    for (int i = 0; i < npoint - 1; ++i) {
        // ---- distance min-update + per-thread argmax (pure register compute) ----
        float bv = -1.0f; int bj = 0;
        {
            #pragma clang fp contract(off)
            #pragma unroll
            for (int j = 0; j < PPT; ++j) {
                float dx = px[j] - cx, dy = py[j] - cy, dz = pz[j] - cz;
                float d  = dx*dx + dy*dy + dz*dz;     // mul/add order matches np ref
                float nd = fminf(dist[j], d);
                dist[j]  = nd;
                if (nd > bv) { bv = nd; bj = j; }     // strict > keeps first index
            }
        }
        // pack: [63:32] float bits (non-neg -> order-preserving)
        //       [16:0]  131071 - idx  (bigger packed == smaller idx on tie)
        //       bits [31:22] reserved for tag at publish time (zero here)
        unsigned long long pk =
              ((unsigned long long)__float_as_uint(bv) << 32)
            | (unsigned long long)(0x1FFFFu - (unsigned)(p0 + bj));

        // ---- wave butterfly max on packed u64 ----
        #pragma unroll
        for (int m = 32; m >= 1; m >>= 1) {
            unsigned long long o = __shfl_xor(pk, m);
            if (o > pk) pk = o;
        }
        if (lane == 0) s_w[wave] = pk;
        __syncthreads();

        unsigned long long* sb =
            slots + ((i & 1) ? PAR : (size_t)0) + (size_t)b * WGB * SLOT_STRIDE;
        const unsigned tag = (unsigned)(i + 1);   // 1..1023, fits 10 bits, never 0

        if (wave == 0) {
            // ---- cross-wave reduce: lanes 0..7 each grab one wave's result ----
            unsigned long long v = s_w[lane & 7];
            #pragma unroll
            for (int m = 4; m >= 1; m >>= 1) {
                unsigned long long o = __shfl_xor(v, m);
                if (o > v) v = o;
            }
            // ---- lane 0 publishes (tag in bits [31:22]); relaxed is sufficient:
            //      the slot word is the entire communicated payload ----
            if (lane == 0) {
                unsigned long long pub = v | ((unsigned long long)tag << 22);
                __hip_atomic_store(sb + (size_t)w * SLOT_STRIDE, pub,
                                   __ATOMIC_RELAXED, __HIP_MEMORY_SCOPE_AGENT);
            }
            // ---- lanes 0..7 poll the 8 padded slots ----
            unsigned long long s = 0;
            if (lane < WGB) {
                unsigned long long* sl = sb + (size_t)lane * SLOT_STRIDE;
                do {
                    s = __hip_atomic_load(sl, __ATOMIC_RELAXED,
                                          __HIP_MEMORY_SCOPE_AGENT);
                } while (((unsigned)(s >> 22) & 1023u) != tag);
            }
            // speculative candidate-coords fetch (overlaps the reduce)
            int idx_l = (int)(0x1FFFFu - (unsigned)(s & 0x1FFFFu));
            float ccx = 0.f, ccy = 0.f, ccz = 0.f;
            if (lane < WGB) {
                const float* cp = base + (size_t)idx_l * 3;
                ccx = cp[0]; ccy = cp[1]; ccz = cp[2];
            }
            // ---- reduce over the 8 slot values (tags equal -> order by val,idx) ----
            unsigned long long mx = s;
            #pragma unroll
            for (int m = 4; m >= 1; m >>= 1) {
                unsigned long long o = __shfl_xor(mx, m);
                if (o > mx) mx = o;
            }
            unsigned long long ball = __ballot(lane < WGB && s == mx);
            int winlane = __ffsll(ball) - 1;
            float wx = __shfl(ccx, winlane);
            float wy = __shfl(ccy, winlane);
            float wz = __shfl(ccz, winlane);
            int  wix = __shfl(idx_l, winlane);
            if (lane == 0) {
                s_c[0] = wx; s_c[1] = wy; s_c[2] = wz;
                if (w == 0) out[b * npoint + (i + 1)] = wix;
            }
        }
        __syncthreads();

        cx = s_c[0]; cy = s_c[1]; cz = s_c[2];
    }
}

extern "C" void kernel_launch(void* const* d_in, const int* in_sizes, int n_in,
                              void* d_out, int out_size, void* d_ws, size_t ws_size,
                              hipStream_t stream) {
    const float* xyz = (const float*)d_in[0];
    int* out = (int*)d_out;
    unsigned long long* slots = (unsigned long long*)d_ws;
    const int npoint = out_size / NBATCH;   // 1024

    // Clear slot region (16 KB) so stale/poisoned tags can never match tag>=1.
    hipMemsetAsync(d_ws, 0,
                   (size_t)2 * NBATCH * WGB * SLOT_STRIDE * sizeof(unsigned long long),
                   stream);

    dim3 grid(NBATCH * WGB);   // 64 WGs, all co-resident -> spin-sync safe
    dim3 block(THREADS);
    fps_kernel<<<grid, block, 0, stream>>>(xyz, out, slots, npoint);
}

// Round 4
// 2135.616 us; speedup vs baseline: 4.2071x; 1.2490x over previous
//
#include <hip/hip_runtime.h>
#include <stdint.h>

// Farthest Point Sampling, B=8, N=131072, npoint=1024.
// 8 batches x 32 WGs x 256 threads (all 256 CUs busy); 16 points/thread held
// in ext_vector SSA registers (no alloca -> compiler cannot demote to scratch).
// b = bid&7 puts each batch's 32 WGs on one XCD (round-robin dispatch heuristic)
// -> xyz and sync slots are XCD-L2-local.
// Cross-WG per-iteration sync via tagged, cache-line-padded slots in d_ws
// (relaxed agent-scope atomics -- the 64-bit slot word is the entire payload).

#define NPTS        131072
#define NBATCH      8
#define WGB         32          // workgroups per batch
#define THREADS     256
#define PPT         16          // points per thread = NPTS / (WGB*THREADS)
#define SLOT_STRIDE 16          // ULLs per slot = 128 B (own cache line)
#define BIGDIST     1e10f

typedef float vf16 __attribute__((ext_vector_type(16)));

__global__ __launch_bounds__(THREADS, 1) void fps_kernel(
        const float* __restrict__ xyz,          // [B, N, 3]
        int* __restrict__ out,                  // [B, npoint]
        unsigned long long* __restrict__ slots, // [2][NBATCH][WGB][SLOT_STRIDE]
        int npoint)
{
    const int bid  = blockIdx.x;
    const int b    = bid & (NBATCH - 1);  // batch; all its WGs on one XCD (heuristic)
    const int w    = bid >> 3;            // 0..31 WG-within-batch
    const int tid  = threadIdx.x;
    const int lane = tid & 63;
    const int wave = tid >> 6;            // 0..3

    const int p0 = w * (THREADS * PPT) + tid * PPT;   // first owned point (within batch)
    const float* base = xyz + (size_t)b * NPTS * 3;

    // ---- one-time load: 16 points = 48 floats = 12 float4, into SSA vectors ----
    const float4* src = reinterpret_cast<const float4*>(base + (size_t)p0 * 3);
    float4 v0 = src[0], v1 = src[1], v2  = src[2],  v3  = src[3];
    float4 v4 = src[4], v5 = src[5], v6  = src[6],  v7  = src[7];
    float4 v8 = src[8], v9 = src[9], v10 = src[10], v11 = src[11];

    // flat[48] laid out x0,y0,z0,x1,... ; px[j]=flat[3j], py[j]=flat[3j+1], pz[j]=flat[3j+2]
    vf16 px = (vf16){ v0.x, v0.w, v1.z, v2.y, v3.x, v3.w, v4.z, v5.y,
                      v6.x, v6.w, v7.z, v8.y, v9.x, v9.w, v10.z, v11.y };
    vf16 py = (vf16){ v0.y, v1.x, v1.w, v2.z, v3.y, v4.x, v4.w, v5.z,
                      v6.y, v7.x, v7.w, v8.z, v9.y, v10.x, v10.w, v11.z };
    vf16 pz = (vf16){ v0.z, v1.y, v2.x, v2.w, v3.z, v4.y, v5.x, v5.w,
                      v6.z, v7.y, v8.x, v8.w, v9.z, v10.y, v11.x, v11.w };
    vf16 dist = BIGDIST;   // splat

    __shared__ unsigned long long s_w[THREADS / 64];  // per-wave reduced packed
    __shared__ float s_c[3];                          // winner coords broadcast

    // initial centroid = point 0 of this batch
    float cx = base[0], cy = base[1], cz = base[2];

    if (w == 0 && tid == 0) out[b * npoint + 0] = 0;

    const size_t PAR = (size_t)NBATCH * WGB * SLOT_STRIDE;  // parity block (ULLs)

    for (int i = 0; i < npoint - 1; ++i) {
        // ---- distance min-update + per-thread argmax (pure register compute) ----
        float bv = -1.0f; int bj = 0;
        {
            #pragma clang fp contract(off)
            #pragma unroll
            for (int j = 0; j < PPT; ++j) {
                float dx = px[j] - cx, dy = py[j] - cy, dz = pz[j] - cz;
                float d  = dx*dx + dy*dy + dz*dz;     // mul/add order matches np ref
                float nd = fminf(dist[j], d);
                dist[j]  = nd;
                if (nd > bv) { bv = nd; bj = j; }     // strict > keeps first index
            }
        }
        // pack: [63:32] float bits (non-neg -> order-preserving)
        //       [16:0]  131071 - idx  (bigger packed == smaller idx on tie)
        //       bits [31:22] hold the tag at publish time (zero here)
        unsigned long long pk =
              ((unsigned long long)__float_as_uint(bv) << 32)
            | (unsigned long long)(0x1FFFFu - (unsigned)(p0 + bj));

        // ---- wave butterfly max on packed u64 ----
        #pragma unroll
        for (int m = 32; m >= 1; m >>= 1) {
            unsigned long long o = __shfl_xor(pk, m);
            if (o > pk) pk = o;
        }
        if (lane == 0) s_w[wave] = pk;
        __syncthreads();

        unsigned long long* sb =
            slots + ((i & 1) ? PAR : (size_t)0) + (size_t)b * WGB * SLOT_STRIDE;
        const unsigned tag = (unsigned)(i + 1);   // 1..1023, fits 10 bits, never 0

        if (wave == 0) {
            // ---- cross-wave reduce over the 4 wave results ----
            unsigned long long v = s_w[lane & 3];
            #pragma unroll
            for (int m = 2; m >= 1; m >>= 1) {
                unsigned long long o = __shfl_xor(v, m);
                if (o > v) v = o;
            }
            // ---- lane 0 publishes (tag in bits [31:22]); relaxed is sufficient:
            //      the slot word is the entire communicated payload ----
            if (lane == 0) {
                unsigned long long pub = v | ((unsigned long long)tag << 22);
                __hip_atomic_store(sb + (size_t)w * SLOT_STRIDE, pub,
                                   __ATOMIC_RELAXED, __HIP_MEMORY_SCOPE_AGENT);
            }
            // ---- lanes 0..31 poll the 32 padded slots ----
            unsigned long long s = 0;
            if (lane < WGB) {
                unsigned long long* sl = sb + (size_t)lane * SLOT_STRIDE;
                do {
                    s = __hip_atomic_load(sl, __ATOMIC_RELAXED,
                                          __HIP_MEMORY_SCOPE_AGENT);
                } while (((unsigned)(s >> 22) & 1023u) != tag);
            }
            // speculative candidate-coords fetch (overlaps the reduce)
            int idx_l = (int)(0x1FFFFu - (unsigned)(s & 0x1FFFFu));
            float ccx = 0.f, ccy = 0.f, ccz = 0.f;
            if (lane < WGB) {
                const float* cp = base + (size_t)idx_l * 3;
                ccx = cp[0]; ccy = cp[1]; ccz = cp[2];
            }
            // ---- reduce over the 32 slot values (same tag -> order by val,idx) ----
            unsigned long long mx = s;
            #pragma unroll
            for (int m = 16; m >= 1; m >>= 1) {
                unsigned long long o = __shfl_xor(mx, m);
                if (o > mx) mx = o;
            }
            unsigned long long ball = __ballot(lane < WGB && s == mx);
            int winlane = __ffsll(ball) - 1;
            float wx = __shfl(ccx, winlane);
            float wy = __shfl(ccy, winlane);
            float wz = __shfl(ccz, winlane);
            int  wix = __shfl(idx_l, winlane);
            if (lane == 0) {
                s_c[0] = wx; s_c[1] = wy; s_c[2] = wz;
                if (w == 0) out[b * npoint + (i + 1)] = wix;
            }
        }
        __syncthreads();

        cx = s_c[0]; cy = s_c[1]; cz = s_c[2];
    }
}

extern "C" void kernel_launch(void* const* d_in, const int* in_sizes, int n_in,
                              void* d_out, int out_size, void* d_ws, size_t ws_size,
                              hipStream_t stream) {
    const float* xyz = (const float*)d_in[0];
    int* out = (int*)d_out;
    unsigned long long* slots = (unsigned long long*)d_ws;
    const int npoint = out_size / NBATCH;   // 1024

    // Clear slot region (64 KB) so stale/poisoned tags can never match tag>=1.
    hipMemsetAsync(d_ws, 0,
                   (size_t)2 * NBATCH * WGB * SLOT_STRIDE * sizeof(unsigned long long),
                   stream);

    dim3 grid(NBATCH * WGB);   // 256 WGs <= 256 CUs -> all co-resident, spin-sync safe
    dim3 block(THREADS);
    fps_kernel<<<grid, block, 0, stream>>>(xyz, out, slots, npoint);
}